// Round 10
// baseline (84.669 us; speedup 1.0000x reference)
//
#include <hip/hip_runtime.h>

// SequentialSparsemax: (8, 16, 262144) f32.
// pass1: sparsemax over 16 instruments at every (b, t).
// pass2: sparsemax over each 64-sample frame per (b, inst).
//
// One wave = one (16 inst x 128 time) tile (2 frames); 16384 waves; 4
// independent waves per 256-thread workgroup (disjoint 4 KiB LDS slices,
// lgkm-only fences, no block barrier).
//   pass1: lane owns 2 times; serial OEMS-16 per time over A[16][2].
//   stage: pass-1 result packed bf16 (v_cvt_pk_bf16_f32) into LDS
//          [16][64] dwords, phys dword = i*64 + (td ^ 4i)  (write free,
//          gather 8 acc/bank = volume-bound, re-read free). A dies here.
//   pass2: each 64-row owned by a LANE PAIR: in-lane OEMS-32 (191 CE),
//          cross-lane bitonic halver (32 swizzle xor-1, paired k/31-k),
//          5-stage in-lane bitonic merge (80 CE). Only w[32] live.
//   tau:   in-lane prefix + partner total (1 swizzle) + max-identity
//          tau = max_k (cs_k-1)*rcp(k); combine via 1 swizzle.
// Peak live ~58 VGPR -> spill-free at __launch_bounds__(256,8)
// (<=64 VGPR, 8 waves/SIMD; LDS 16 KiB/WG not binding).

#define T_DIM   262144
#define N_INST  16
#define B_DIM   8
#define CHUNK   128                   // time samples per wave-tile (2 frames)
#define NCHUNK  (T_DIM / CHUNK)       // 2048
#define WPB     4                     // independent waves per block

// Batcher odd-even mergesort, descending; all indices compile-time after
// full unroll (pure SSA, 2 VALU per CE). 63 CE for N=16, 191 for N=32.
template<int N>
__device__ __forceinline__ void sort_desc_oems(float (&a)[N]) {
#pragma unroll
  for (int p = 1; p < N; p <<= 1) {
#pragma unroll
    for (int k = p; k >= 1; k >>= 1) {
#pragma unroll
      for (int j = k & (p - 1); j + k < N; j += 2 * k) {
#pragma unroll
        for (int i = 0; i < k; ++i) {
          if (i + j + k < N &&
              (i + j) / (2 * p) == (i + j + k) / (2 * p)) {
            const float x = a[i + j], y = a[i + j + k];
            a[i + j]     = fmaxf(x, y);   // descending
            a[i + j + k] = fminf(x, y);
          }
        }
      }
    }
  }
}

// One stage of an all-descending bitonic merge (input bitonic).
template<int N, int S>
__device__ __forceinline__ void bmerge_desc_stage(float (&a)[N]) {
#pragma unroll
  for (int j = 0; j < N; ++j) {
    const int l = j ^ S;
    if (l > j) {
      const float x = a[j], y = a[l];
      a[j] = fmaxf(x, y);
      a[l] = fminf(x, y);
    }
  }
}

// z sorted descending. tau = max_k (cs_k - 1)/k (exact max-identity:
// h(k) rises exactly while the reference's support condition holds).
template<int N>
__device__ __forceinline__ float sparsemax_tau(const float (&z)[N]) {
  float cs = z[0];
  float tau = cs - 1.0f;  // k = 1
#pragma unroll
  for (int k = 1; k < N; ++k) {
    cs += z[k];
    tau = fmaxf(tau, (cs - 1.0f) * (1.0f / (float)(k + 1)));
  }
  return tau;
}

// lane XOR-1 exchange within 32-lane groups (BitMode swizzle).
__device__ __forceinline__ float swz_xor1(float x) {
  return __int_as_float(__builtin_amdgcn_ds_swizzle(
      __float_as_int(x), (1 << 10) | 0x1f));
}

// lgkm-only fence: orders this wave's own-LDS ops without draining vmcnt.
// Waves within the block use disjoint LDS slices => no s_barrier.
__device__ __forceinline__ void lds_fence() {
  asm volatile("s_waitcnt lgkmcnt(0)" ::: "memory");
  __builtin_amdgcn_sched_barrier(0);
}

// RNE pack of two f32 into bf16x2 (lo16 = first operand).
__device__ __forceinline__ unsigned pack_bf16(float lo, float hi) {
  unsigned r;
  asm("v_cvt_pk_bf16_f32 %0, %1, %2" : "=v"(r) : "v"(lo), "v"(hi));
  return r;
}

__device__ __forceinline__ float bf_lo(unsigned d) {
  return __int_as_float((int)(d << 16));
}
__device__ __forceinline__ float bf_hi(unsigned d) {
  return __int_as_float((int)(d & 0xFFFF0000u));
}

__global__ __launch_bounds__(256, 8) void seq_sparsemax_kernel(
    const float* __restrict__ in, float* __restrict__ out) {
  __shared__ unsigned lds[WPB * N_INST * 64];  // 4 waves x 4 KiB = 16 KiB

  const int lane = threadIdx.x & 63;
  const int wave = threadIdx.x >> 6;
  unsigned* __restrict__ sp = &lds[wave * N_INST * 64];

  const int tid   = blockIdx.x * WPB + wave;   // tile index 0..16383
  const int b     = tid >> 11;                 // / NCHUNK
  const int chunk = tid & (NCHUNK - 1);
  const size_t base = (size_t)b * N_INST * T_DIM + (size_t)chunk * CHUNK + 2 * lane;

  // ---- load: A[i][j] = in[b, i, t0 + 2*lane + j], coalesced float2 ----
  float A[N_INST][2];
#pragma unroll
  for (int i = 0; i < N_INST; ++i) {
    const float2 v = *reinterpret_cast<const float2*>(in + base + (size_t)i * T_DIM);
    A[i][0] = v.x; A[i][1] = v.y;
  }

  // ---- pass 1: sparsemax over instruments at each of this lane's 2 times ----
  float t1[2];
#pragma unroll
  for (int j = 0; j < 2; ++j) {
    float z[N_INST];
#pragma unroll
    for (int i = 0; i < N_INST; ++i) z[i] = A[i][j];
    sort_desc_oems<16>(z);
    t1[j] = sparsemax_tau(z);
  }

  // ---- stage pass-1 result to LDS as bf16; A dies here ----
  // lane's 2 times = logical dword td = lane of each inst row (lo16 = even
  // time). Physical dword for (inst i, td): i*64 + (td ^ 4i).
#pragma unroll
  for (int i = 0; i < N_INST; ++i) {
    const unsigned pk = pack_bf16(fmaxf(A[i][0] - t1[0], 0.0f),
                                  fmaxf(A[i][1] - t1[1], 0.0f));
    sp[i * 64 + (lane ^ (4 * i))] = pk;
  }
  lds_fence();  // RAW: writes visible to this wave's cross-lane reads

  // ---- gather pass-2 half-row: lane pair (2r, 2r+1) owns row r ----
  // row r = f2*16 + i2... here r = lane>>1: i2 = r&15, f2 = r>>4;
  // half h = lane&1 takes times f2*64 + h*32 + [0,32).
  const int r  = lane >> 1;
  const int h  = lane & 1;
  const int i2 = r & 15;
  const int f2 = r >> 4;
  float w[32];
  {
    const int tdbase = f2 * 32 + h * 16;
#pragma unroll
    for (int v = 0; v < 4; ++v) {
      const int pd = i2 * 64 + ((tdbase + 4 * v) ^ (4 * i2));
      const uint4 d = *reinterpret_cast<const uint4*>(&sp[pd]);
      w[8 * v + 0] = bf_lo(d.x); w[8 * v + 1] = bf_hi(d.x);
      w[8 * v + 2] = bf_lo(d.y); w[8 * v + 3] = bf_hi(d.y);
      w[8 * v + 4] = bf_lo(d.z); w[8 * v + 5] = bf_hi(d.z);
      w[8 * v + 6] = bf_lo(d.w); w[8 * v + 7] = bf_hi(d.w);
    }
  }

  // ---- pass 2a: in-lane sort of 32 (descending) ----
  sort_desc_oems<32>(w);

  // ---- pass 2b: cross-lane bitonic halver with partner (xor-1) ----
  // slot k pairs my w[k] with partner w[31-k]; lane0 keeps max, lane1 min.
  // Pairs (k, 31-k) handled together so originals are read before writes.
#pragma unroll
  for (int k = 0; k < 16; ++k) {
    const float ya = swz_xor1(w[31 - k]);  // partner's w[31-k] for slot k
    const float yb = swz_xor1(w[k]);       // partner's w[k] for slot 31-k
    if (h == 0) {
      w[k]      = fmaxf(w[k], ya);
      w[31 - k] = fmaxf(w[31 - k], yb);
    } else {
      w[k]      = fminf(w[k], ya);
      w[31 - k] = fminf(w[31 - k], yb);
    }
  }

  // ---- pass 2c: in-lane bitonic merge (5 stages) -> sorted descending;
  //      lane0 = z_1..z_32, lane1 = z_33..z_64 of the row ----
  bmerge_desc_stage<32, 16>(w);
  bmerge_desc_stage<32, 8>(w);
  bmerge_desc_stage<32, 4>(w);
  bmerge_desc_stage<32, 2>(w);
  bmerge_desc_stage<32, 1>(w);

  // ---- tau over the distributed 64: prefix + partner total + max-id ----
#pragma unroll
  for (int j = 1; j < 32; ++j) w[j] += w[j - 1];   // in-lane prefix
  const float ptot = swz_xor1(w[31]);              // partner's total
  const float off  = h ? ptot : 0.0f;              // lane1 offset = lane0 sum
  const float kb   = (float)(h * 32 + 1);          // k at j=0
  float best = -__builtin_inff();
#pragma unroll
  for (int j = 0; j < 32; ++j) {
    const float cs = off + w[j];
    best = fmaxf(best, (cs - 1.0f) * __builtin_amdgcn_rcpf(kb + (float)j));
  }
  best = fmaxf(best, swz_xor1(best));   // both lanes of the pair: row tau
  __builtin_amdgcn_sched_barrier(0);    // don't hoist phase 3 into the sort

  // ---- phase 3: pull row-taus, re-read own LDS dwords, store float2 ----
  // tau for (inst i, frame f1) lives at lane 2*(f1*16+i) = (lane&32)|2i.
  const int slb = lane & 32;
#pragma unroll
  for (int i = 0; i < N_INST; ++i) {
    const float taui = __int_as_float(__builtin_amdgcn_ds_bpermute(
        (slb | (2 * i)) << 2, __float_as_int(best)));
    const unsigned d = sp[i * 64 + (lane ^ (4 * i))];
    float2 o;
    o.x = fmaxf(bf_lo(d) - taui, 0.0f);
    o.y = fmaxf(bf_hi(d) - taui, 0.0f);
    *reinterpret_cast<float2*>(out + base + (size_t)i * T_DIM) = o;
  }
}

extern "C" void kernel_launch(void* const* d_in, const int* in_sizes, int n_in,
                              void* d_out, int out_size, void* d_ws, size_t ws_size,
                              hipStream_t stream) {
  const float* in = (const float*)d_in[0];
  float* out = (float*)d_out;
  const int grid = B_DIM * NCHUNK / WPB;  // 4096 blocks x 4 waves
  seq_sparsemax_kernel<<<grid, 64 * WPB, 0, stream>>>(in, out);
}

// Round 11
// 46.012 us; speedup vs baseline: 1.8401x; 1.8401x over previous
//
#include <hip/hip_runtime.h>

// SequentialSparsemax: (8, 16, 262144) f32.
// pass1: sparsemax over 16 instruments at every (b, t).
// pass2: sparsemax over each 64-sample frame per (b, inst).
//
// r9's memory shape (one wave = 16x256 tile, float4 loads/stores, WPB=4)
// with the register footprint halved via packed-f16 SIMD-in-register:
//   pass1: Ah[16][2] u32 (2 times/reg); ONE packed OEMS-16 (v_pk_max/min)
//          sorts both times at once; tau in f32 via inline unpack.
//   pass2: w[32] packed (e,e+32): 480/543 OEMS-64 CEs are lo/hi pairs
//          (1 instr/CE); 32 within-reg + 31 cross CEs use merge forms.
//   staging: xor-8 ds_swizzle partner exchange builds (t,t+32) dwords;
//          12-slot LDS (6 KiB/wave, 2-round r3-style; insts 0..3
//          recomputed from Ah at phase 3). Slot-XOR keeps DS volume-bound.
// Peak live ~60 VGPR -> __launch_bounds__(256,8): <=64 regs, no AGPR,
// no scratch. LDS 24 KiB/WG -> 24-wave/CU cap.

#define T_DIM   262144
#define N_INST  16
#define B_DIM   8
#define CHUNK   256                   // time samples per wave-tile (4 frames)
#define NCHUNK  (T_DIM / CHUNK)       // 1024
#define WPB     4                     // independent waves per block
#define NSLOT   12                    // LDS slots per wave (12 x 128 dwords)

// ---- packed-f16 micro-ops (u32 = 2 x f16) ----
__device__ __forceinline__ unsigned pk_max(unsigned a, unsigned b) {
  unsigned r; asm("v_pk_max_f16 %0, %1, %2" : "=v"(r) : "v"(a), "v"(b)); return r;
}
__device__ __forceinline__ unsigned pk_min(unsigned a, unsigned b) {
  unsigned r; asm("v_pk_min_f16 %0, %1, %2" : "=v"(r) : "v"(a), "v"(b)); return r;
}
__device__ __forceinline__ unsigned pk_add(unsigned a, unsigned b) {
  unsigned r; asm("v_pk_add_f16 %0, %1, %2" : "=v"(r) : "v"(a), "v"(b)); return r;
}
__device__ __forceinline__ unsigned f2h(float x) {   // low16 valid, RNE
  unsigned r; asm("v_cvt_f16_f32 %0, %1" : "=v"(r) : "v"(x)); return r;
}
__device__ __forceinline__ float h2f(unsigned x) {   // converts low16
  float r; asm("v_cvt_f32_f16 %0, %1" : "=v"(r) : "v"(x)); return r;
}
__device__ __forceinline__ unsigned hswap(unsigned x) { return (x >> 16) | (x << 16); }
__device__ __forceinline__ unsigned lh(unsigned lo, unsigned hi) {
  return (lo & 0xFFFFu) | (hi & 0xFFFF0000u);   // [lo.lo16, hi.hi16] -> v_bfi
}
__device__ __forceinline__ unsigned packh(unsigned lo, unsigned hi) {
  return (lo & 0xFFFFu) | (hi << 16);           // both low16-valid inputs
}

// ---- CE helpers: float (scalar) and unsigned (packed f16 pair) ----
__device__ __forceinline__ float    ce_max(float a, float b)       { return fmaxf(a, b); }
__device__ __forceinline__ float    ce_min(float a, float b)       { return fminf(a, b); }
__device__ __forceinline__ unsigned ce_max(unsigned a, unsigned b) { return pk_max(a, b); }
__device__ __forceinline__ unsigned ce_min(unsigned a, unsigned b) { return pk_min(a, b); }

// Batcher odd-even mergesort, descending (max to lower index), uniform
// direction; all indices compile-time after unroll. For T=unsigned each
// half of the register is an independent problem (packed SIMD sort).
template<typename T, int N>
__device__ __forceinline__ void sort_desc_oems(T (&a)[N]) {
#pragma unroll
  for (int p = 1; p < N; p <<= 1) {
#pragma unroll
    for (int k = p; k >= 1; k >>= 1) {
#pragma unroll
      for (int j = k & (p - 1); j + k < N; j += 2 * k) {
#pragma unroll
        for (int i = 0; i < k; ++i) {
          if (i + j + k < N && (i + j) / (2 * p) == (i + j + k) / (2 * p)) {
            const T x = a[i + j], y = a[i + j + k];
            a[i + j]     = ce_max(x, y);
            a[i + j + k] = ce_min(x, y);
          }
        }
      }
    }
  }
}

// OEMS-64 on (e, e+32) split-packing: reg r = [pos r, pos r+32].
// CE classes: both<32 -> plain pk pair (covers hi companion, which the
// network provably contains); y==x+32 -> within-register; x<32<=y -> cross
// (reg x lo <-> reg y-32 hi); x>=32 -> companion, already handled.
__device__ __forceinline__ void sort64_packed(unsigned (&a)[32]) {
#pragma unroll
  for (int p = 1; p < 64; p <<= 1) {
#pragma unroll
    for (int k = p; k >= 1; k >>= 1) {
#pragma unroll
      for (int j = k & (p - 1); j + k < 64; j += 2 * k) {
#pragma unroll
        for (int i = 0; i < k; ++i) {
          const int x = i + j, y = i + j + k;
          if (y < 64 && (x / (2 * p)) == (y / (2 * p))) {
            if (y < 32) {
              const unsigned A = a[x], B = a[y];
              a[x] = pk_max(A, B); a[y] = pk_min(A, B);
            } else if (x < 32) {
              if (y == x + 32) {              // within-register: [max,min]
                const unsigned A = a[x], S = hswap(A);
                a[x] = lh(pk_max(A, S), pk_min(A, S));
              } else {                        // cross: x lo <-> (y-32) hi
                const int ry = y - 32;
                const unsigned A = a[x], B = a[ry], Bs = hswap(B);
                const unsigned M = pk_max(A, Bs), m = pk_min(A, Bs);
                a[x]  = lh(M, A);             // lo=max(A.lo,B.hi), hi kept
                a[ry] = lh(B, hswap(m));      // lo kept, hi=min(A.lo,B.hi)
              }
            }
          }
        }
      }
    }
  }
}

// lgkm-only fence: orders this wave's own-LDS ops without draining vmcnt.
// Waves in the block use disjoint LDS slices => no s_barrier.
__device__ __forceinline__ void lds_fence() {
  asm volatile("s_waitcnt lgkmcnt(0)" ::: "memory");
  __builtin_amdgcn_sched_barrier(0);
}

__device__ __forceinline__ unsigned swz_xor8(unsigned x) {
  return (unsigned)__builtin_amdgcn_ds_swizzle((int)x, (8 << 10) | 0x1f);
}

__global__ __launch_bounds__(256, 8) void seq_sparsemax_kernel(
    const float* __restrict__ in, float* __restrict__ out) {
  __shared__ __align__(16) unsigned lds[WPB * NSLOT * 128];  // 24 KiB

  const int lane = threadIdx.x & 63;
  const int wave = threadIdx.x >> 6;
  unsigned* __restrict__ sp = &lds[wave * NSLOT * 128];

  const int tid   = blockIdx.x * WPB + wave;   // tile index 0..8191
  const int b     = tid >> 10;
  const int chunk = tid & (NCHUNK - 1);
  const size_t base = (size_t)b * N_INST * T_DIM + (size_t)chunk * CHUNK + 4 * lane;

  const int f    = lane >> 4;          // this lane's frame (of 4)
  const int lt0  = 4 * (lane & 15);    // local time in frame, 0..60
  const bool lol = (lane & 8) == 0;    // lt0 < 32 (owns packed-dword writes)

  // ---- load float4, convert to packed f16: Ah[i] = [(t0,t1),(t2,t3)] ----
  unsigned Ah[N_INST][2];
#pragma unroll
  for (int i = 0; i < N_INST; ++i) {
    const float4 q = *reinterpret_cast<const float4*>(in + base + (size_t)i * T_DIM);
    Ah[i][0] = packh(f2h(q.x), f2h(q.y));
    Ah[i][1] = packh(f2h(q.z), f2h(q.w));
  }

  // ---- pass 1: packed OEMS-16 sorts both times of a pair at once ----
  unsigned nt2[2];   // packed negated taus, [-tau_even, -tau_odd]
#pragma unroll
  for (int p = 0; p < 2; ++p) {
    unsigned z[N_INST];
#pragma unroll
    for (int i = 0; i < N_INST; ++i) z[i] = Ah[i][p];
    sort_desc_oems<unsigned, N_INST>(z);
    float csl = 0.f, csh = 0.f, tl = -1e30f, th = -1e30f;
#pragma unroll
    for (int k = 0; k < N_INST; ++k) {
      csl += h2f(z[k]);       tl = fmaxf(tl, (csl - 1.f) * (1.f / (float)(k + 1)));
      csh += h2f(z[k] >> 16); th = fmaxf(th, (csh - 1.f) * (1.f / (float)(k + 1)));
    }
    nt2[p] = packh(f2h(tl), f2h(th)) ^ 0x80008000u;   // negate both halves
  }

  // Y(i,p) = pk_max(Ah + (-tau), 0): pass-1 result, packed f16.
  const unsigned zz = 0u;

  // ---- staging + gather, 2 rounds (12-slot LDS, r3 overwrite scheme) ----
  // logical dword d of (slot s, frame fr) holds times (d, d+32) of that row;
  // physical dword = s*128 + fr*32 + (d ^ ((s&7)<<2)).
  const int i2 = lane & 15;            // this lane's pass-2 row: inst
  const int f2 = lane >> 4;            //                         frame
  const int sw_w = 0;                  // (placeholder; per-slot swizzle below)
  unsigned w[32];

#pragma unroll
  for (int g = 0; g < 2; ++g) {
    if (g > 0) lds_fence();            // WAR: round-A reads done
    const int i_lo = (g == 0) ? 0 : 12, i_hi = (g == 0) ? 12 : 16;
#pragma unroll
    for (int i = 0; i < N_INST; ++i) {
      if (i < i_lo || i >= i_hi) continue;
      const unsigned y0 = pk_max(pk_add(Ah[i][0], nt2[0]), zz);
      const unsigned y1 = pk_max(pk_add(Ah[i][1], nt2[1]), zz);
      const unsigned p0 = swz_xor8(y0);   // partner lane (^8): times +32
      const unsigned p1 = swz_xor8(y1);
      if (lol) {
        uint4 d;
        d.x = packh(y0, p0);              // [t=lt0+0, t+32]
        d.y = lh(y0 >> 16, p0);           // [t=lt0+1, t+32]
        d.z = packh(y1, p1);              // [t=lt0+2, t+32]
        d.w = lh(y1 >> 16, p1);           // [t=lt0+3, t+32]
        const int s = (i < 12) ? i : (i - 12);
        const int pd = s * 128 + f * 32 + (lt0 ^ ((s & 7) << 2));
        *reinterpret_cast<uint4*>(&sp[pd]) = d;
      }
    }
    lds_fence();                        // RAW: writes visible
    const bool mine = (g == 0) ? (i2 < 12) : (i2 >= 12);
    if (mine) {
      const int s = (i2 < 12) ? i2 : (i2 - 12);
#pragma unroll
      for (int v = 0; v < 8; ++v) {
        const int pd = s * 128 + f2 * 32 + ((4 * v) ^ ((s & 7) << 2));
        const uint4 d = *reinterpret_cast<const uint4*>(&sp[pd]);
        w[4 * v + 0] = d.x; w[4 * v + 1] = d.y;
        w[4 * v + 2] = d.z; w[4 * v + 3] = d.w;
      }
    }
  }

  // ---- pass 2: packed sort of this lane's 64-row, then tau (f32) ----
  sort64_packed(w);
  float cs = 0.f, best = -1e30f;
#pragma unroll
  for (int r = 0; r < 32; ++r) {        // ranks 1..32 (lo halves)
    cs += h2f(w[r]);
    best = fmaxf(best, (cs - 1.f) * (1.f / (float)(r + 1)));
  }
#pragma unroll
  for (int r = 0; r < 32; ++r) {        // ranks 33..64 (hi halves)
    cs += h2f(w[r] >> 16);
    best = fmaxf(best, (cs - 1.f) * (1.f / (float)(r + 33)));
  }
  __builtin_amdgcn_sched_barrier(0);    // don't hoist phase 3 into the sort

  // ---- phase 3: pull row-taus; Y from LDS (i>=4) or recompute (i<4) ----
  const int slb = lane & 48;            // (lane>>4)*16: row-owner lane base
  const unsigned hsh = (lane & 8) ? 16u : 0u;   // my half in packed dwords
#pragma unroll
  for (int i = 0; i < N_INST; ++i) {
    const float taui = __int_as_float(__builtin_amdgcn_ds_bpermute(
        (slb | i) << 2, __float_as_int(best)));
    float y0, y1, y2, y3;
    if (i < 4) {                        // slots overwritten: recompute from Ah
      const unsigned a0 = pk_max(pk_add(Ah[i][0], nt2[0]), zz);
      const unsigned a1 = pk_max(pk_add(Ah[i][1], nt2[1]), zz);
      y0 = h2f(a0); y1 = h2f(a0 >> 16); y2 = h2f(a1); y3 = h2f(a1 >> 16);
    } else {
      const int s = (i < 12) ? i : (i - 12);
      const int pd = s * 128 + f * 32 + ((lt0 & 31) ^ ((s & 7) << 2));
      const uint4 d = *reinterpret_cast<const uint4*>(&sp[pd]);
      y0 = h2f(d.x >> hsh); y1 = h2f(d.y >> hsh);
      y2 = h2f(d.z >> hsh); y3 = h2f(d.w >> hsh);
    }
    float4 o;
    o.x = fmaxf(y0 - taui, 0.0f);
    o.y = fmaxf(y1 - taui, 0.0f);
    o.z = fmaxf(y2 - taui, 0.0f);
    o.w = fmaxf(y3 - taui, 0.0f);
    *reinterpret_cast<float4*>(out + base + (size_t)i * T_DIM) = o;
  }
  (void)sw_w;
}

extern "C" void kernel_launch(void* const* d_in, const int* in_sizes, int n_in,
                              void* d_out, int out_size, void* d_ws, size_t ws_size,
                              hipStream_t stream) {
  const float* in = (const float*)d_in[0];
  float* out = (float*)d_out;
  const int grid = B_DIM * NCHUNK / WPB;  // 2048 blocks x 4 waves
  seq_sparsemax_kernel<<<grid, 64 * WPB, 0, stream>>>(in, out);
}